// Round 3
// baseline (991.700 us; speedup 1.0000x reference)
//
#include <hip/hip_runtime.h>
#include <hip/hip_bf16.h>

#define IN_CH 128
#define HID   16
#define N1_T  100000
#define N2_T  10000
#define OUT_CH 64

// ---------------------------------------------------------------------------
// Kernel 1: xp = x @ W1   (500000x128 @ 128x16).
// 64-row LDS tile; each wave owns a wave-uniform 4-channel group so W1 reads
// become scalar (s_load) through the constant cache; xs reads are b128
// k-vectorized (32 LDS instrs/thread instead of 256).
// ---------------------------------------------------------------------------
constexpr int PROJ_ROWS = 64;
constexpr int XS_STRIDE = 132;  // floats; 132*4=528B rows stay 16B-aligned

__global__ __launch_bounds__(256) void proj_kernel(
    const float* __restrict__ x, const float* __restrict__ W1,
    float* __restrict__ xp, int n0) {
  __shared__ float xs[PROJ_ROWS * XS_STRIDE];

  const int tid = threadIdx.x;
  const int rowBase = blockIdx.x * PROJ_ROWS;

  // stage 64x128 x-tile as float4 (2048 float4, 8/thread, coalesced)
  const float4* x4 = reinterpret_cast<const float4*>(x + (size_t)rowBase * IN_CH);
  #pragma unroll
  for (int i = 0; i < 8; ++i) {
    int f = tid + i * 256;      // float4 index within tile
    int r = f >> 5;             // 32 float4 per row
    int c4 = f & 31;
    if (rowBase + r < n0) {
      *reinterpret_cast<float4*>(&xs[r * XS_STRIDE + c4 * 4]) = x4[f];
    }
  }
  __syncthreads();

  const int lane = tid & 63;  // row within tile
  // wave-uniform channel group -> force into SGPR so W1 loads scalarize
  const int c0 = __builtin_amdgcn_readfirstlane((tid >> 6) << 2);

  const float* xrow = &xs[lane * XS_STRIDE];
  float a0 = 0.f, a1 = 0.f, a2 = 0.f, a3 = 0.f;
  #pragma unroll
  for (int k = 0; k < IN_CH; k += 4) {
    float4 xv = *reinterpret_cast<const float4*>(xrow + k);  // ds_read_b128
    // scalar (wave-uniform) W1 reads: W1[k+j][c0..c0+3]
    float4 w0 = *reinterpret_cast<const float4*>(W1 + (k + 0) * HID + c0);
    float4 w1 = *reinterpret_cast<const float4*>(W1 + (k + 1) * HID + c0);
    float4 w2 = *reinterpret_cast<const float4*>(W1 + (k + 2) * HID + c0);
    float4 w3 = *reinterpret_cast<const float4*>(W1 + (k + 3) * HID + c0);
    a0 += xv.x * w0.x + xv.y * w1.x + xv.z * w2.x + xv.w * w3.x;
    a1 += xv.x * w0.y + xv.y * w1.y + xv.z * w2.y + xv.w * w3.y;
    a2 += xv.x * w0.z + xv.y * w1.z + xv.z * w2.z + xv.w * w3.z;
    a3 += xv.x * w0.w + xv.y * w1.w + xv.z * w2.w + xv.w * w3.w;
  }

  const int orow = rowBase + lane;
  if (orow < n0) {
    *reinterpret_cast<float4*>(&xp[(size_t)orow * HID + c0]) =
        make_float4(a0, a1, a2, a3);
  }
}

// ---------------------------------------------------------------------------
// Kernel 2/4: edge aggregation in 16-dim space. 4 lanes per edge, each lane
// gathers one float4 (64B/edge coalesced) and issues 4 f32 atomics.
// ---------------------------------------------------------------------------
__global__ __launch_bounds__(256) void aggregate16(
    const float* __restrict__ feat, const int* __restrict__ src,
    const int* __restrict__ dst, int E,
    float* __restrict__ summed, float* __restrict__ cnt) {
  const int total = E * 4;                       // ≤ 8M, fits int
  const int stride = gridDim.x * blockDim.x;
  for (int t = blockIdx.x * blockDim.x + threadIdx.x; t < total; t += stride) {
    const int e = t >> 2;
    const int q = t & 3;
    const int s = src[e];
    const int d = dst[e];
    const float4 v =
        *reinterpret_cast<const float4*>(&feat[(size_t)s * HID + q * 4]);
    float* base = &summed[(size_t)d * HID + q * 4];
    atomicAdd(base + 0, v.x);
    atomicAdd(base + 1, v.y);
    atomicAdd(base + 2, v.z);
    atomicAdd(base + 3, v.w);
    if (q == 0) atomicAdd(&cnt[d], 1.0f);
  }
}

// ---------------------------------------------------------------------------
// Kernel 3: h1 = relu(summed1 / max(cnt1,1) + b1), float4-vectorized.
// ---------------------------------------------------------------------------
__global__ __launch_bounds__(256) void finalize1_kernel(
    const float* __restrict__ summed, const float* __restrict__ cnt,
    const float* __restrict__ b1, float* __restrict__ h1, int n1) {
  const int t = blockIdx.x * blockDim.x + threadIdx.x;  // one float4 each
  if (t >= n1 * 4) return;
  const int row = t >> 2;
  const float inv = 1.0f / fmaxf(cnt[row], 1.0f);
  const float4 s = reinterpret_cast<const float4*>(summed)[t];
  const float4 b = reinterpret_cast<const float4*>(b1)[t & 3];
  float4 o;
  o.x = fmaxf(s.x * inv + b.x, 0.0f);
  o.y = fmaxf(s.y * inv + b.y, 0.0f);
  o.z = fmaxf(s.z * inv + b.z, 0.0f);
  o.w = fmaxf(s.w * inv + b.w, 0.0f);
  reinterpret_cast<float4*>(h1)[t] = o;
}

// ---------------------------------------------------------------------------
// Kernel 5: h2 = mean2 @ W2 + b2, then log_softmax per row.
// One 64-lane wave per output row (OUT_CH == 64 == wavefront).
// ---------------------------------------------------------------------------
__global__ __launch_bounds__(256) void out_kernel(
    const float* __restrict__ summed2, const float* __restrict__ cnt2,
    const float* __restrict__ W2, const float* __restrict__ b2,
    float* __restrict__ out, int n2) {
  const int row = blockIdx.x * 4 + (threadIdx.x >> 6);
  if (row >= n2) return;
  const int c = threadIdx.x & 63;

  const float inv = 1.0f / fmaxf(cnt2[row], 1.0f);
  float acc = b2[c];
  #pragma unroll
  for (int k = 0; k < HID; ++k) {
    acc += summed2[(size_t)row * HID + k] * inv * W2[k * OUT_CH + c];
  }
  // wave-wide (64-lane) max
  float mx = acc;
  #pragma unroll
  for (int off = 32; off > 0; off >>= 1) mx = fmaxf(mx, __shfl_xor(mx, off));
  float ex = expf(acc - mx);
  float sum = ex;
  #pragma unroll
  for (int off = 32; off > 0; off >>= 1) sum += __shfl_xor(sum, off);
  out[(size_t)row * OUT_CH + c] = acc - mx - logf(sum);
}

// ---------------------------------------------------------------------------
extern "C" void kernel_launch(void* const* d_in, const int* in_sizes, int n_in,
                              void* d_out, int out_size, void* d_ws, size_t ws_size,
                              hipStream_t stream) {
  const float* x   = (const float*)d_in[0];
  const float* W1  = (const float*)d_in[1];
  const float* b1  = (const float*)d_in[2];
  const float* W2  = (const float*)d_in[3];
  const float* b2  = (const float*)d_in[4];
  const int* src1  = (const int*)d_in[5];
  const int* dst1  = (const int*)d_in[6];
  const int* src2  = (const int*)d_in[7];
  const int* dst2  = (const int*)d_in[8];

  const int n0 = in_sizes[0] / IN_CH;   // 500000
  const int E1 = in_sizes[5];           // 2000000
  const int E2 = in_sizes[7];           // 400000

  float* ws      = (float*)d_ws;
  float* xp      = ws;                              // n0*16
  float* summed1 = xp + (size_t)n0 * HID;           // N1*16
  float* cnt1    = summed1 + (size_t)N1_T * HID;    // N1
  float* summed2 = cnt1 + N1_T;                     // N2*16
  float* cnt2    = summed2 + (size_t)N2_T * HID;    // N2
  float* h1      = cnt2 + N2_T;                     // N1*16

  float* out = (float*)d_out;

  // zero the accumulators (contiguous region: summed1|cnt1|summed2|cnt2)
  const size_t zero_floats =
      (size_t)N1_T * HID + N1_T + (size_t)N2_T * HID + N2_T;
  hipMemsetAsync(summed1, 0, zero_floats * sizeof(float), stream);

  // 1) xp = x @ W1
  const int proj_blocks = (n0 + PROJ_ROWS - 1) / PROJ_ROWS;
  proj_kernel<<<proj_blocks, 256, 0, stream>>>(x, W1, xp, n0);

  // 2) layer-1 aggregation (atomics into summed1/cnt1)
  aggregate16<<<4096, 256, 0, stream>>>(xp, src1, dst1, E1, summed1, cnt1);

  // 3) h1 = relu(mean + b1)
  finalize1_kernel<<<(N1_T * 4 + 255) / 256, 256, 0, stream>>>(
      summed1, cnt1, b1, h1, N1_T);

  // 4) layer-2 aggregation
  aggregate16<<<2048, 256, 0, stream>>>(h1, src2, dst2, E2, summed2, cnt2);

  // 5) h2 + log_softmax
  out_kernel<<<(N2_T + 3) / 4, 256, 0, stream>>>(
      summed2, cnt2, W2, b2, out, N2_T);
}

// Round 4
// 608.998 us; speedup vs baseline: 1.6284x; 1.6284x over previous
//
#include <hip/hip_runtime.h>
#include <hip/hip_bf16.h>

#define IN_CH 128
#define HID   16
#define N1_T  100000
#define N2_T  10000
#define OUT_CH 64

// ---------------------------------------------------------------------------
// Kernel 1: xp = x @ W1   (500000x128 @ 128x16).
// 64-row LDS tile; each wave owns a wave-uniform 4-channel group so W1 reads
// become scalar (s_load) through the constant cache; xs reads are b128
// k-vectorized.
// ---------------------------------------------------------------------------
constexpr int PROJ_ROWS = 64;
constexpr int XS_STRIDE = 132;  // floats; 132*4=528B rows stay 16B-aligned

__global__ __launch_bounds__(256) void proj_kernel(
    const float* __restrict__ x, const float* __restrict__ W1,
    float* __restrict__ xp, int n0) {
  __shared__ float xs[PROJ_ROWS * XS_STRIDE];

  const int tid = threadIdx.x;
  const int rowBase = blockIdx.x * PROJ_ROWS;

  // stage 64x128 x-tile as float4 (2048 float4, 8/thread, coalesced)
  const float4* x4 = reinterpret_cast<const float4*>(x + (size_t)rowBase * IN_CH);
  #pragma unroll
  for (int i = 0; i < 8; ++i) {
    int f = tid + i * 256;      // float4 index within tile
    int r = f >> 5;             // 32 float4 per row
    int c4 = f & 31;
    if (rowBase + r < n0) {
      *reinterpret_cast<float4*>(&xs[r * XS_STRIDE + c4 * 4]) = x4[f];
    }
  }
  __syncthreads();

  const int lane = tid & 63;  // row within tile
  // wave-uniform channel group -> force into SGPR so W1 loads scalarize
  const int c0 = __builtin_amdgcn_readfirstlane((tid >> 6) << 2);

  const float* xrow = &xs[lane * XS_STRIDE];
  float a0 = 0.f, a1 = 0.f, a2 = 0.f, a3 = 0.f;
  #pragma unroll
  for (int k = 0; k < IN_CH; k += 4) {
    float4 xv = *reinterpret_cast<const float4*>(xrow + k);  // ds_read_b128
    float4 w0 = *reinterpret_cast<const float4*>(W1 + (k + 0) * HID + c0);
    float4 w1 = *reinterpret_cast<const float4*>(W1 + (k + 1) * HID + c0);
    float4 w2 = *reinterpret_cast<const float4*>(W1 + (k + 2) * HID + c0);
    float4 w3 = *reinterpret_cast<const float4*>(W1 + (k + 3) * HID + c0);
    a0 += xv.x * w0.x + xv.y * w1.x + xv.z * w2.x + xv.w * w3.x;
    a1 += xv.x * w0.y + xv.y * w1.y + xv.z * w2.y + xv.w * w3.y;
    a2 += xv.x * w0.z + xv.y * w1.z + xv.z * w2.z + xv.w * w3.z;
    a3 += xv.x * w0.w + xv.y * w1.w + xv.z * w2.w + xv.w * w3.w;
  }

  const int orow = rowBase + lane;
  if (orow < n0) {
    *reinterpret_cast<float4*>(&xp[(size_t)orow * HID + c0]) =
        make_float4(a0, a1, a2, a3);
  }
}

// ---------------------------------------------------------------------------
// Kernel 2: build per-target linked lists.  head[d] = last edge id, nxt[e]
// chains.  One int atomicExch per edge (vs 16 f32 atomics before).
// nxt is only read by LATER kernel launches, so the exch/write pair needs no
// intra-kernel ordering.
// ---------------------------------------------------------------------------
__global__ __launch_bounds__(256) void build_list(
    const int* __restrict__ dst, int E, int* head, int* __restrict__ nxt) {
  const int stride = gridDim.x * blockDim.x;
  for (int t = blockIdx.x * blockDim.x + threadIdx.x; t < E; t += stride) {
    const int d = dst[t];
    const int old = atomicExch(&head[d], t);
    nxt[t] = old;
  }
}

// ---------------------------------------------------------------------------
// Kernel 3/4: per-target list walk + mean (+ optional bias/relu).
// 4 lanes per row; lane q owns channels [4q,4q+4) as a float4 accumulator.
// All gathers are plain loads (feat is L3/L2-resident).
// ---------------------------------------------------------------------------
__global__ __launch_bounds__(256) void agg_layer(
    const float* __restrict__ feat, const int* __restrict__ srcArr,
    const int* __restrict__ head, const int* __restrict__ nxt,
    const float* __restrict__ bias, float* __restrict__ outFeat,
    int nrows, int doReluBias) {
  const int gid = blockIdx.x * blockDim.x + threadIdx.x;
  const int row = gid >> 2;
  const int q = gid & 3;
  if (row >= nrows) return;

  int e = head[row];
  float4 acc = make_float4(0.f, 0.f, 0.f, 0.f);
  int cnt = 0;
  while (e >= 0) {
    const int s = srcArr[e];
    const float4 v =
        *reinterpret_cast<const float4*>(&feat[(size_t)s * HID + q * 4]);
    acc.x += v.x; acc.y += v.y; acc.z += v.z; acc.w += v.w;
    ++cnt;
    e = nxt[e];
  }
  const float inv = 1.0f / (float)(cnt > 0 ? cnt : 1);
  float4 r;
  r.x = acc.x * inv; r.y = acc.y * inv; r.z = acc.z * inv; r.w = acc.w * inv;
  if (doReluBias) {
    const float4 b = reinterpret_cast<const float4*>(bias)[q];
    r.x = fmaxf(r.x + b.x, 0.f);
    r.y = fmaxf(r.y + b.y, 0.f);
    r.z = fmaxf(r.z + b.z, 0.f);
    r.w = fmaxf(r.w + b.w, 0.f);
  }
  *reinterpret_cast<float4*>(&outFeat[(size_t)row * HID + q * 4]) = r;
}

// ---------------------------------------------------------------------------
// Kernel 5: h2 = mean2 @ W2 + b2, then log_softmax per row.
// One 64-lane wave per output row (OUT_CH == 64 == wavefront).
// ---------------------------------------------------------------------------
__global__ __launch_bounds__(256) void out_kernel(
    const float* __restrict__ mean2, const float* __restrict__ W2,
    const float* __restrict__ b2, float* __restrict__ out, int n2) {
  const int row = blockIdx.x * 4 + (threadIdx.x >> 6);
  if (row >= n2) return;
  const int c = threadIdx.x & 63;

  float acc = b2[c];
  #pragma unroll
  for (int k = 0; k < HID; ++k) {
    acc += mean2[(size_t)row * HID + k] * W2[k * OUT_CH + c];
  }
  float mx = acc;
  #pragma unroll
  for (int off = 32; off > 0; off >>= 1) mx = fmaxf(mx, __shfl_xor(mx, off));
  float ex = expf(acc - mx);
  float sum = ex;
  #pragma unroll
  for (int off = 32; off > 0; off >>= 1) sum += __shfl_xor(sum, off);
  out[(size_t)row * OUT_CH + c] = acc - mx - logf(sum);
}

// ---------------------------------------------------------------------------
extern "C" void kernel_launch(void* const* d_in, const int* in_sizes, int n_in,
                              void* d_out, int out_size, void* d_ws, size_t ws_size,
                              hipStream_t stream) {
  const float* x   = (const float*)d_in[0];
  const float* W1  = (const float*)d_in[1];
  const float* b1  = (const float*)d_in[2];
  const float* W2  = (const float*)d_in[3];
  const float* b2  = (const float*)d_in[4];
  const int* src1  = (const int*)d_in[5];
  const int* dst1  = (const int*)d_in[6];
  const int* src2  = (const int*)d_in[7];
  const int* dst2  = (const int*)d_in[8];

  const int n0 = in_sizes[0] / IN_CH;   // 500000
  const int E1 = in_sizes[5];           // 2000000
  const int E2 = in_sizes[7];           // 400000

  // workspace layout (element offsets; all float4-aligned where needed)
  float* ws    = (float*)d_ws;
  float* xp    = ws;                                  // n0*16      = 8.0M
  float* h1    = xp + (size_t)n0 * HID;               // N1*16      = 1.6M
  float* mean2 = h1 + (size_t)N1_T * HID;             // N2*16      = 160K
  int*   head  = (int*)(mean2 + (size_t)N2_T * HID);  // N1+N2      = 110K
  int*   nxt1  = head + (N1_T + N2_T);                // E1         = 2.0M
  int*   nxt2  = nxt1 + E1;                           // E2         = 400K

  float* out = (float*)d_out;

  // head sentinel: 0xFFFFFFFF == -1
  hipMemsetAsync(head, 0xFF, (size_t)(N1_T + N2_T) * sizeof(int), stream);

  // build linked lists (layer 1 into head[0..N1), layer 2 into head[N1..))
  build_list<<<1024, 256, 0, stream>>>(dst1, E1, head, nxt1);
  build_list<<<256, 256, 0, stream>>>(dst2, E2, head + N1_T, nxt2);

  // xp = x @ W1
  const int proj_blocks = (n0 + PROJ_ROWS - 1) / PROJ_ROWS;
  proj_kernel<<<proj_blocks, 256, 0, stream>>>(x, W1, xp, n0);

  // layer-1: h1 = relu(mean(xp over neighbors) + b1)
  agg_layer<<<(N1_T * 4 + 255) / 256, 256, 0, stream>>>(
      xp, src1, head, nxt1, b1, h1, N1_T, 1);

  // layer-2: mean2 = mean(h1 over neighbors)
  agg_layer<<<(N2_T * 4 + 255) / 256, 256, 0, stream>>>(
      h1, src2, head + N1_T, nxt2, nullptr, mean2, N2_T, 0);

  // h2 = mean2 @ W2 + b2, log_softmax
  out_kernel<<<(N2_T + 3) / 4, 256, 0, stream>>>(mean2, W2, b2, out, N2_T);
}